// Round 1
// baseline (299.036 us; speedup 1.0000x reference)
//
#include <hip/hip_runtime.h>
#include <hip/hip_bf16.h>
#include <stdint.h>

// Problem constants
#define B_ 4
#define C_ 64
#define T_ 80
#define H_ 36
#define W_ 64
#define N_ 128
#define NT_ 10
#define S_ (H_*W_)        // 2304 = K of the GEMM
#define M_ (B_*C_*T_)     // 20480 = rows of the GEMM
#define K_ S_
#define TOUT (T_-NT_+1)   // 71

#define BM 32
#define BK 64

using float4v = __attribute__((ext_vector_type(4))) float;
using short8v = __attribute__((ext_vector_type(8))) short;

// round-to-nearest-even fp32 -> bf16 bits
__device__ __forceinline__ unsigned short f2bf(float f) {
  unsigned int u = __float_as_uint(f);
  u += 0x7fffu + ((u >> 16) & 1u);
  return (unsigned short)(u >> 16);
}

__device__ __forceinline__ unsigned int pkbf(float a, float b) {
  union { __hip_bfloat162 h2; unsigned int u; } cv;
  cv.h2 = __float22bfloat162_rn(make_float2(a, b));
  return cv.u;
}

// async global->LDS, 16B per lane (lds dest = wave-uniform base + lane*16)
__device__ __forceinline__ void glds16(const void* g, void* l) {
  __builtin_amdgcn_global_load_lds(
      (const __attribute__((address_space(1))) unsigned int*)g,
      (__attribute__((address_space(3))) unsigned int*)l, 16, 0, 0);
}

// ---------------------------------------------------------------------------
// K1: Gaussian soft-pool weights, normalized, written fragment-packed bf16:
//     Bp[((s>>3)*N + n)*8 + (s&7)]  i.e. [K/8][N][8]
// ---------------------------------------------------------------------------
__global__ __launch_bounds__(256) void k1_ws(const float* __restrict__ wx,
                                             const float* __restrict__ wy,
                                             const float* __restrict__ wsigx,
                                             const float* __restrict__ wsigy,
                                             unsigned short* __restrict__ Bp) {
  const int n = blockIdx.x;
  const int tid = threadIdx.x;
  const float cx = wx[n], cy = wy[n];
  const float rx = fmaxf(wsigx[n], 0.f);
  const float ry = fmaxf(wsigy[n], 0.f);
  const float i2sx = 0.5f / (0.1f + rx * rx);
  const float i2sy = 0.5f / (0.1f + ry * ry);

  float ev[9];   // 2304 = 9*256, each thread owns s = tid + i*256
  float part = 0.f;
#pragma unroll
  for (int i = 0; i < 9; ++i) {
    const int s = tid + i * 256;
    const int h = s >> 6, w = s & 63;
    const float dx = (w - 31.5f) * (1.f / 64.f) - cx;  // (w - W/2 + .5)/W
    const float dy = (h - 17.5f) * (1.f / 36.f) - cy;  // (h - H/2 + .5)/H
    const float e = __expf(-(dx * dx * i2sx + dy * dy * i2sy));
    ev[i] = e;
    part += e;
  }
#pragma unroll
  for (int off = 32; off > 0; off >>= 1) part += __shfl_down(part, off);
  __shared__ float red[4];
  if ((tid & 63) == 0) red[tid >> 6] = part;
  __syncthreads();
  const float inv = 1.f / (0.1f + red[0] + red[1] + red[2] + red[3]);
#pragma unroll
  for (int i = 0; i < 9; ++i) {
    const int s = tid + i * 256;
    Bp[((s >> 3) * N_ + n) * 8 + (s & 7)] = f2bf(ev[i] * inv);
  }
}

// ---------------------------------------------------------------------------
// K2: Z[m,n] = sum_k A[m,k] * ws[k,n]   (M=20480, K=2304, N=128)
// BM=32 x BN=128 x BK=64, 256 threads = 4 waves.
// Wave (wm,wn): rows wm*16..+15, cols wn*64..+63 (4 n-tiles of 16).
// As: fp32, XOR-swizzled 16B chunks: chunk(r, c4) stored at r*16 + (c4^(r&15))
// Bs: bf16, packed [8 kgroups][128 n][8 k-inner] -> b-frag = 1 ds_read_b128
// ---------------------------------------------------------------------------
__global__ __launch_bounds__(256, 4) void k2_gemm(const float* __restrict__ A,
                                                  const unsigned short* __restrict__ Bp,
                                                  float* __restrict__ Z) {
  __shared__ float4v As[BM * 16];   // 512 chunks, 8 KB
  __shared__ short8v Bs[8 * N_];    // 1024 chunks, 16 KB
  const int tid = threadIdx.x;
  const int lane = tid & 63;
  const int wv = tid >> 6;
  const int wm = wv & 1;
  const int wn = wv >> 1;
  const int m15 = lane & 15;
  const int q = lane >> 4;
  const int mBase = blockIdx.x * BM;

  float4v acc[4];
#pragma unroll
  for (int i = 0; i < 4; ++i) acc[i] = (float4v)(0.f);

  for (int k0 = 0; k0 < K_; k0 += BK) {
    // stage A (32 rows x 64 fp32 = 512 chunks, swizzled)
#pragma unroll
    for (int i = 0; i < 2; ++i) {
      const int lam = i * 256 + tid;
      const int r = lam >> 4;
      const int c4 = (lam & 15) ^ (r & 15);
      glds16(A + (size_t)(mBase + r) * K_ + k0 + c4 * 4, &As[lam]);
    }
    // stage B (8 contiguous kgroups = 16 KB, linear)
#pragma unroll
    for (int i = 0; i < 4; ++i) {
      const int lam = i * 256 + tid;
      glds16(Bp + (size_t)k0 * N_ + lam * 8, &Bs[lam]);
    }
    __syncthreads();

#pragma unroll
    for (int ks = 0; ks < 2; ++ks) {
      // a-frag: A[row][ks*32 + q*8 + j], 8 fp32 = 2 swizzled chunks -> bf16
      const int c4a = ks * 8 + q * 2;
      const int rowc = (wm * 16 + m15) * 16;
      const float4v alo = As[rowc + (c4a ^ m15)];
      const float4v ahi = As[rowc + ((c4a + 1) ^ m15)];
      union { short8v s8; unsigned int u[4]; } af;
      af.u[0] = pkbf(alo[0], alo[1]);
      af.u[1] = pkbf(alo[2], alo[3]);
      af.u[2] = pkbf(ahi[0], ahi[1]);
      af.u[3] = pkbf(ahi[2], ahi[3]);
      const int g = ks * 4 + q;
#pragma unroll
      for (int nt = 0; nt < 4; ++nt) {
        const short8v bf = Bs[g * N_ + wn * 64 + nt * 16 + m15];
        acc[nt] = __builtin_amdgcn_mfma_f32_16x16x32_bf16(af.s8, bf, acc[nt], 0, 0, 0);
      }
    }
    __syncthreads();
  }

  // C/D layout: col = lane&15 (n), row = q*4 + reg
#pragma unroll
  for (int nt = 0; nt < 4; ++nt) {
#pragma unroll
    for (int v = 0; v < 4; ++v) {
      Z[(size_t)(mBase + wm * 16 + q * 4 + v) * N_ + wn * 64 + nt * 16 + m15] =
          acc[nt][v];
    }
  }
}

// ---------------------------------------------------------------------------
// K3: R[b,t,n] = sum_c Z[(b*C+c)*T+t, n] * wc[c,n]
// ---------------------------------------------------------------------------
__global__ __launch_bounds__(128) void k3_reduce_c(const float* __restrict__ Z,
                                                   const float* __restrict__ wc,
                                                   float* __restrict__ R) {
  const int n = threadIdx.x;
  const int bt = blockIdx.x;       // b*T + t
  const int b = bt / T_;
  const int t = bt - b * T_;
  float s = 0.f;
#pragma unroll 8
  for (int c = 0; c < C_; ++c) {
    s += Z[(size_t)((b * C_ + c) * T_ + t) * N_ + n] * wc[c * N_ + n];
  }
  R[(b * T_ + t) * N_ + n] = s;
}

// ---------------------------------------------------------------------------
// K4: out[b,n,tau] = sum_j R[b, tau+j, n] * wt[j,n] + wb[n]
// ---------------------------------------------------------------------------
__global__ __launch_bounds__(128) void k4_conv(const float* __restrict__ R,
                                               const float* __restrict__ wt,
                                               const float* __restrict__ wb,
                                               float* __restrict__ out) {
  const int n = threadIdx.x;
  const int tau = blockIdx.x;      // 0..70
  const int b = blockIdx.y;
  float s = wb[n];
#pragma unroll
  for (int j = 0; j < NT_; ++j) {
    s += R[(b * T_ + tau + j) * N_ + n] * wt[j * N_ + n];
  }
  out[((size_t)b * N_ + n) * TOUT + tau] = s;
}

extern "C" void kernel_launch(void* const* d_in, const int* in_sizes, int n_in,
                              void* d_out, int out_size, void* d_ws, size_t ws_size,
                              hipStream_t stream) {
  (void)in_sizes; (void)n_in; (void)out_size; (void)ws_size;
  const float* x    = (const float*)d_in[0];
  // d_in[1] = targets (unused by reference)
  const float* wc   = (const float*)d_in[2];
  const float* wx   = (const float*)d_in[3];
  const float* wy   = (const float*)d_in[4];
  const float* wsx  = (const float*)d_in[5];
  const float* wsy  = (const float*)d_in[6];
  const float* wt   = (const float*)d_in[7];
  const float* wb   = (const float*)d_in[8];
  float* out = (float*)d_out;

  char* ws = (char*)d_ws;
  unsigned short* Bp = (unsigned short*)ws;              // 2304*128*2 = 589824 B
  float* R = (float*)(ws + 589824);                      // 320*128*4  = 163840 B
  float* Z = (float*)(ws + 589824 + 163840);             // 20480*128*4 = 10485760 B

  k1_ws<<<N_, 256, 0, stream>>>(wx, wy, wsx, wsy, Bp);
  k2_gemm<<<M_ / BM, 256, 0, stream>>>(x, Bp, Z);
  k3_reduce_c<<<B_ * T_, 128, 0, stream>>>(Z, wc, R);
  dim3 g4(TOUT, B_);
  k4_conv<<<g4, 128, 0, stream>>>(R, wt, wb, out);
}

// Round 2
// 296.993 us; speedup vs baseline: 1.0069x; 1.0069x over previous
//
#include <hip/hip_runtime.h>
#include <hip/hip_bf16.h>
#include <stdint.h>

// Problem constants
#define B_ 4
#define C_ 64
#define T_ 80
#define H_ 36
#define W_ 64
#define N_ 128
#define NT_ 10
#define S_ (H_*W_)        // 2304 = K of the GEMM
#define M_ (B_*C_*T_)     // 20480 = rows of the GEMM
#define K_ S_
#define TOUT (T_-NT_+1)   // 71

#define BM 32
#define BK 64
#define KSPLIT 2
#define NIT (K_ / (BK * KSPLIT))   // 18 iters per block

using float4v = __attribute__((ext_vector_type(4))) float;
using short8v = __attribute__((ext_vector_type(8))) short;

// round-to-nearest-even fp32 -> bf16 bits
__device__ __forceinline__ unsigned short f2bf(float f) {
  unsigned int u = __float_as_uint(f);
  u += 0x7fffu + ((u >> 16) & 1u);
  return (unsigned short)(u >> 16);
}

__device__ __forceinline__ unsigned int pkbf(float a, float b) {
  union { __hip_bfloat162 h2; unsigned int u; } cv;
  cv.h2 = __float22bfloat162_rn(make_float2(a, b));
  return cv.u;
}

// async global->LDS, 16B per lane (lds dest = wave-uniform base + lane*16)
__device__ __forceinline__ void glds16(const void* g, void* l) {
  __builtin_amdgcn_global_load_lds(
      (const __attribute__((address_space(1))) unsigned int*)g,
      (__attribute__((address_space(3))) unsigned int*)l, 16, 0, 0);
}

// ---------------------------------------------------------------------------
// K1: Gaussian soft-pool weights, normalized, written fragment-packed bf16:
//     Bp[((s>>3)*N + n)*8 + (s&7)]  i.e. [K/8][N][8]
// ---------------------------------------------------------------------------
__global__ __launch_bounds__(256) void k1_ws(const float* __restrict__ wx,
                                             const float* __restrict__ wy,
                                             const float* __restrict__ wsigx,
                                             const float* __restrict__ wsigy,
                                             unsigned short* __restrict__ Bp) {
  const int n = blockIdx.x;
  const int tid = threadIdx.x;
  const float cx = wx[n], cy = wy[n];
  const float rx = fmaxf(wsigx[n], 0.f);
  const float ry = fmaxf(wsigy[n], 0.f);
  const float i2sx = 0.5f / (0.1f + rx * rx);
  const float i2sy = 0.5f / (0.1f + ry * ry);

  float ev[9];   // 2304 = 9*256, each thread owns s = tid + i*256
  float part = 0.f;
#pragma unroll
  for (int i = 0; i < 9; ++i) {
    const int s = tid + i * 256;
    const int h = s >> 6, w = s & 63;
    const float dx = (w - 31.5f) * (1.f / 64.f) - cx;  // (w - W/2 + .5)/W
    const float dy = (h - 17.5f) * (1.f / 36.f) - cy;  // (h - H/2 + .5)/H
    const float e = __expf(-(dx * dx * i2sx + dy * dy * i2sy));
    ev[i] = e;
    part += e;
  }
#pragma unroll
  for (int off = 32; off > 0; off >>= 1) part += __shfl_down(part, off);
  __shared__ float red[4];
  if ((tid & 63) == 0) red[tid >> 6] = part;
  __syncthreads();
  const float inv = 1.f / (0.1f + red[0] + red[1] + red[2] + red[3]);
#pragma unroll
  for (int i = 0; i < 9; ++i) {
    const int s = tid + i * 256;
    Bp[((s >> 3) * N_ + n) * 8 + (s & 7)] = f2bf(ev[i] * inv);
  }
}

// ---------------------------------------------------------------------------
// K2: Zp[split][m,n] = sum_{k in split} A[m,k] * ws[k,n]
//   M=20480, K=2304 (split x2), N=128. BM=32 x BN=128 x BK=64, 4 waves.
//   Wave wv owns cols wv*32..+31 (2 n-tiles) x all 32 rows (2 m-tiles).
//   A: fp32 in LDS, double-buffered, XOR-swizzled 16B chunks:
//      chunk(r,c4) at r*16 + (c4 ^ (r&15)).  B: bf16 frags direct from L2.
// ---------------------------------------------------------------------------
__global__ __launch_bounds__(256, 4) void k2_gemm(const float* __restrict__ A,
                                                  const unsigned short* __restrict__ Bp,
                                                  float* __restrict__ Zp) {
  __shared__ float4v As[2][BM * 16];   // 2 x 8 KB
  const int tid = threadIdx.x;
  const int lane = tid & 63;
  const int wv = tid >> 6;             // wave's 32-col strip
  const int m15 = lane & 15;
  const int q = lane >> 4;
  const int mBase = blockIdx.x * BM;
  const int split = blockIdx.y;
  const int kStart = split * (K_ / KSPLIT);

  // A staging: 512 chunks/tile, 2 per thread
  const float* ga[2];
  int lam_[2];
#pragma unroll
  for (int i = 0; i < 2; ++i) {
    const int lam = i * 256 + tid;
    const int r = lam >> 4;
    const int c4 = (lam & 15) ^ (r & 15);
    ga[i] = A + (size_t)(mBase + r) * K_ + kStart + c4 * 4;
    lam_[i] = lam;
  }

  float4v acc[2][2];                   // [mt][nt]
#pragma unroll
  for (int i = 0; i < 2; ++i)
#pragma unroll
    for (int j = 0; j < 2; ++j) acc[i][j] = (float4v)(0.f);

  // prologue: stage k-tile 0 into buf 0
#pragma unroll
  for (int i = 0; i < 2; ++i) glds16(ga[i], &As[0][lam_[i]]);

  int cur = 0;
  for (int it = 0; it < NIT; ++it) {
    __syncthreads();                   // buf[cur] ready for all waves
    if (it + 1 < NIT) {                // prefetch next tile into buf[cur^1]
#pragma unroll
      for (int i = 0; i < 2; ++i)
        glds16(ga[i] + (size_t)(it + 1) * BK, &As[cur ^ 1][lam_[i]]);
    }
    const int kg0 = (kStart + it * BK) >> 3;
#pragma unroll
    for (int ks = 0; ks < 2; ++ks) {
      // a-frags for both m-tiles: 8 fp32 = 2 swizzled chunks -> bf16
      const int c4a = ks * 8 + q * 2;
      union { short8v s8; unsigned int u[4]; } af[2];
#pragma unroll
      for (int mt = 0; mt < 2; ++mt) {
        const int rowc = (mt * 16 + m15) * 16;
        const float4v alo = As[cur][rowc + (c4a ^ m15)];
        const float4v ahi = As[cur][rowc + ((c4a + 1) ^ m15)];
        af[mt].u[0] = pkbf(alo[0], alo[1]);
        af[mt].u[1] = pkbf(alo[2], alo[3]);
        af[mt].u[2] = pkbf(ahi[0], ahi[1]);
        af[mt].u[3] = pkbf(ahi[2], ahi[3]);
      }
      const int kg = kg0 + ks * 4 + q;
#pragma unroll
      for (int nt = 0; nt < 2; ++nt) {
        const int col = wv * 32 + nt * 16 + m15;
        const short8v bf =
            *(const short8v*)(Bp + ((size_t)kg * N_ + col) * 8);
        acc[0][nt] = __builtin_amdgcn_mfma_f32_16x16x32_bf16(af[0].s8, bf, acc[0][nt], 0, 0, 0);
        acc[1][nt] = __builtin_amdgcn_mfma_f32_16x16x32_bf16(af[1].s8, bf, acc[1][nt], 0, 0, 0);
      }
    }
    cur ^= 1;
  }

  // C/D layout: col = lane&15, row = q*4 + reg
  float* Z = Zp + (size_t)split * M_ * N_;
#pragma unroll
  for (int mt = 0; mt < 2; ++mt)
#pragma unroll
    for (int nt = 0; nt < 2; ++nt)
#pragma unroll
      for (int v = 0; v < 4; ++v)
        Z[(size_t)(mBase + mt * 16 + q * 4 + v) * N_ + wv * 32 + nt * 16 + m15] =
            acc[mt][nt][v];
}

// ---------------------------------------------------------------------------
// K3: R[b,t,n] = sum_c (Z0+Z1)[(b*C+c)*T+t, n] * wc[c,n]
// ---------------------------------------------------------------------------
__global__ __launch_bounds__(128) void k3_reduce_c(const float* __restrict__ Zp,
                                                   const float* __restrict__ wc,
                                                   float* __restrict__ R) {
  const int n = threadIdx.x;
  const int bt = blockIdx.x;       // b*T + t
  const int b = bt / T_;
  const int t = bt - b * T_;
  const float* Z0 = Zp;
  const float* Z1 = Zp + (size_t)M_ * N_;
  float s = 0.f;
#pragma unroll 8
  for (int c = 0; c < C_; ++c) {
    const size_t idx = (size_t)((b * C_ + c) * T_ + t) * N_ + n;
    s += (Z0[idx] + Z1[idx]) * wc[c * N_ + n];
  }
  R[(b * T_ + t) * N_ + n] = s;
}

// ---------------------------------------------------------------------------
// K4: out[b,n,tau] = sum_j R[b, tau+j, n] * wt[j,n] + wb[n]
// ---------------------------------------------------------------------------
__global__ __launch_bounds__(128) void k4_conv(const float* __restrict__ R,
                                               const float* __restrict__ wt,
                                               const float* __restrict__ wb,
                                               float* __restrict__ out) {
  const int n = threadIdx.x;
  const int tau = blockIdx.x;      // 0..70
  const int b = blockIdx.y;
  float s = wb[n];
#pragma unroll
  for (int j = 0; j < NT_; ++j) {
    s += R[(b * T_ + tau + j) * N_ + n] * wt[j * N_ + n];
  }
  out[((size_t)b * N_ + n) * TOUT + tau] = s;
}

extern "C" void kernel_launch(void* const* d_in, const int* in_sizes, int n_in,
                              void* d_out, int out_size, void* d_ws, size_t ws_size,
                              hipStream_t stream) {
  (void)in_sizes; (void)n_in; (void)out_size; (void)ws_size;
  const float* x    = (const float*)d_in[0];
  // d_in[1] = targets (unused by reference)
  const float* wc   = (const float*)d_in[2];
  const float* wx   = (const float*)d_in[3];
  const float* wy   = (const float*)d_in[4];
  const float* wsx  = (const float*)d_in[5];
  const float* wsy  = (const float*)d_in[6];
  const float* wt   = (const float*)d_in[7];
  const float* wb   = (const float*)d_in[8];
  float* out = (float*)d_out;

  char* ws = (char*)d_ws;
  unsigned short* Bp = (unsigned short*)ws;              // 2304*128*2 = 589824 B
  float* R = (float*)(ws + 589824);                      // 320*128*4  = 163840 B
  float* Zp = (float*)(ws + 589824 + 163840);            // 2*20480*128*4 = 20971520 B

  k1_ws<<<N_, 256, 0, stream>>>(wx, wy, wsx, wsy, Bp);
  dim3 g2(M_ / BM, KSPLIT);
  k2_gemm<<<g2, 256, 0, stream>>>(x, Bp, Zp);
  k3_reduce_c<<<B_ * T_, 128, 0, stream>>>(Zp, wc, R);
  dim3 g4(TOUT, B_);
  k4_conv<<<g4, 128, 0, stream>>>(R, wt, wb, out);
}

// Round 3
// 285.744 us; speedup vs baseline: 1.0465x; 1.0394x over previous
//
#include <hip/hip_runtime.h>
#include <hip/hip_bf16.h>
#include <stdint.h>

// Problem constants
#define B_ 4
#define C_ 64
#define T_ 80
#define H_ 36
#define W_ 64
#define N_ 128
#define NT_ 10
#define S_ (H_*W_)        // 2304 = K of the GEMM
#define M_ (B_*C_*T_)     // 20480 = rows of the GEMM
#define K_ S_
#define TOUT (T_-NT_+1)   // 71

#define BM 64             // = C_: one block owns all channels of one (b,t)
#define BK 64
#define KSPLIT 4
#define KCH (K_ / KSPLIT) // 576
#define NIT (KCH / BK)    // 9 iters

using float4v = __attribute__((ext_vector_type(4))) float;
using short8v = __attribute__((ext_vector_type(8))) short;

// round-to-nearest-even fp32 -> bf16 bits
__device__ __forceinline__ unsigned short f2bf(float f) {
  unsigned int u = __float_as_uint(f);
  u += 0x7fffu + ((u >> 16) & 1u);
  return (unsigned short)(u >> 16);
}

__device__ __forceinline__ unsigned int pkbf(float a, float b) {
  union { __hip_bfloat162 h2; unsigned int u; } cv;
  cv.h2 = __float22bfloat162_rn(make_float2(a, b));
  return cv.u;
}

// async global->LDS, 16B per lane (lds dest = wave-uniform base + lane*16)
__device__ __forceinline__ void glds16(const void* g, void* l) {
  __builtin_amdgcn_global_load_lds(
      (const __attribute__((address_space(1))) unsigned int*)g,
      (__attribute__((address_space(3))) unsigned int*)l, 16, 0, 0);
}

// ---------------------------------------------------------------------------
// K1: Gaussian soft-pool weights, normalized, written fragment-packed bf16:
//     Bp[((s>>3)*N + n)*8 + (s&7)]  i.e. [K/8][N][8]
// ---------------------------------------------------------------------------
__global__ __launch_bounds__(256) void k1_ws(const float* __restrict__ wx,
                                             const float* __restrict__ wy,
                                             const float* __restrict__ wsigx,
                                             const float* __restrict__ wsigy,
                                             unsigned short* __restrict__ Bp) {
  const int n = blockIdx.x;
  const int tid = threadIdx.x;
  const float cx = wx[n], cy = wy[n];
  const float rx = fmaxf(wsigx[n], 0.f);
  const float ry = fmaxf(wsigy[n], 0.f);
  const float i2sx = 0.5f / (0.1f + rx * rx);
  const float i2sy = 0.5f / (0.1f + ry * ry);

  float ev[9];   // 2304 = 9*256, each thread owns s = tid + i*256
  float part = 0.f;
#pragma unroll
  for (int i = 0; i < 9; ++i) {
    const int s = tid + i * 256;
    const int h = s >> 6, w = s & 63;
    const float dx = (w - 31.5f) * (1.f / 64.f) - cx;  // (w - W/2 + .5)/W
    const float dy = (h - 17.5f) * (1.f / 36.f) - cy;  // (h - H/2 + .5)/H
    const float e = __expf(-(dx * dx * i2sx + dy * dy * i2sy));
    ev[i] = e;
    part += e;
  }
#pragma unroll
  for (int off = 32; off > 0; off >>= 1) part += __shfl_down(part, off);
  __shared__ float red[4];
  if ((tid & 63) == 0) red[tid >> 6] = part;
  __syncthreads();
  const float inv = 1.f / (0.1f + red[0] + red[1] + red[2] + red[3]);
#pragma unroll
  for (int i = 0; i < 9; ++i) {
    const int s = tid + i * 256;
    Bp[((s >> 3) * N_ + n) * 8 + (s & 7)] = f2bf(ev[i] * inv);
  }
}

// ---------------------------------------------------------------------------
// K2 (fused): for block (bt, split):
//   Z[c, n] = sum_{k in split} x[(b*C+c)*T+t, k] * ws[k, n]   (c = 0..63)
//   R[bt, n] += sum_c wc[c,n] * Z[c,n]      (atomicAdd of k-split partial)
// BM=64 x BN=128 x BK=64, 256 threads = 4 waves; wave wv owns cols wv*32..+31.
// A: fp32 LDS double-buffered, XOR-swizzled 16B chunks:
//    chunk(r,c4) at r*16 + (c4 ^ (r&15)).  B: bf16 frags direct from L2.
// ---------------------------------------------------------------------------
__global__ __launch_bounds__(256, 4) void k2_fused(const float* __restrict__ A,
                                                   const unsigned short* __restrict__ Bp,
                                                   const float* __restrict__ wc,
                                                   float* __restrict__ R) {
  __shared__ float4v As[2][BM * 16];   // 2 x 16 KB
  const int tid = threadIdx.x;
  const int lane = tid & 63;
  const int wv = tid >> 6;             // wave's 32-col strip
  const int m15 = lane & 15;
  const int q = lane >> 4;
  const int bt = blockIdx.x;           // b*T + t
  const int b = bt / T_;
  const int t = bt - b * T_;
  const int split = blockIdx.y;
  const int kStart = split * KCH;

  // A staging: 1024 chunks/tile, 4 per thread; row r <-> channel c=r
  const float* ga[4];
  int lam_[4];
#pragma unroll
  for (int i = 0; i < 4; ++i) {
    const int lam = i * 256 + tid;
    const int r = lam >> 4;
    const int c4 = (lam & 15) ^ (r & 15);
    ga[i] = A + (size_t)((b * C_ + r) * T_ + t) * K_ + kStart + c4 * 4;
    lam_[i] = lam;
  }

  float4v acc[4][2];                   // [mt][nt]
#pragma unroll
  for (int i = 0; i < 4; ++i)
#pragma unroll
    for (int j = 0; j < 2; ++j) acc[i][j] = (float4v)(0.f);

  // prologue: stage k-tile 0 into buf 0
#pragma unroll
  for (int i = 0; i < 4; ++i) glds16(ga[i], &As[0][lam_[i]]);

  int cur = 0;
  for (int it = 0; it < NIT; ++it) {
    __syncthreads();                   // buf[cur] ready for all waves
    if (it + 1 < NIT) {                // prefetch next tile into buf[cur^1]
#pragma unroll
      for (int i = 0; i < 4; ++i)
        glds16(ga[i] + (size_t)(it + 1) * BK, &As[cur ^ 1][lam_[i]]);
    }
    const int kg0 = (kStart + it * BK) >> 3;
#pragma unroll
    for (int ks = 0; ks < 2; ++ks) {
      const int kg = kg0 + ks * 4 + q;
      const short8v bf0 =
          *(const short8v*)(Bp + ((size_t)kg * N_ + wv * 32 + m15) * 8);
      const short8v bf1 =
          *(const short8v*)(Bp + ((size_t)kg * N_ + wv * 32 + 16 + m15) * 8);
      const int c4a = ks * 8 + q * 2;
#pragma unroll
      for (int mt = 0; mt < 4; ++mt) {
        const int rowc = (mt * 16 + m15) * 16;
        const float4v alo = As[cur][rowc + (c4a ^ m15)];
        const float4v ahi = As[cur][rowc + ((c4a + 1) ^ m15)];
        union { short8v s8; unsigned int u[4]; } af;
        af.u[0] = pkbf(alo[0], alo[1]);
        af.u[1] = pkbf(alo[2], alo[3]);
        af.u[2] = pkbf(ahi[0], ahi[1]);
        af.u[3] = pkbf(ahi[2], ahi[3]);
        acc[mt][0] = __builtin_amdgcn_mfma_f32_16x16x32_bf16(af.s8, bf0, acc[mt][0], 0, 0, 0);
        acc[mt][1] = __builtin_amdgcn_mfma_f32_16x16x32_bf16(af.s8, bf1, acc[mt][1], 0, 0, 0);
      }
    }
    cur ^= 1;
  }

  // Epilogue: C/D layout col = lane&15, row = q*4 + reg; row == channel c.
  // partial over this lane's 16 channels, butterfly over q, one atomic per n.
#pragma unroll
  for (int nt = 0; nt < 2; ++nt) {
    const int n = wv * 32 + nt * 16 + m15;
    float p = 0.f;
#pragma unroll
    for (int mt = 0; mt < 4; ++mt)
#pragma unroll
      for (int v = 0; v < 4; ++v)
        p += acc[mt][nt][v] * wc[(mt * 16 + q * 4 + v) * N_ + n];
    p += __shfl_xor(p, 16);
    p += __shfl_xor(p, 32);
    if (q == 0) atomicAdd(&R[(size_t)bt * N_ + n], p);
  }
}

// ---------------------------------------------------------------------------
// K4: out[b,n,tau] = sum_j R[b, tau+j, n] * wt[j,n] + wb[n]
// ---------------------------------------------------------------------------
__global__ __launch_bounds__(128) void k4_conv(const float* __restrict__ R,
                                               const float* __restrict__ wt,
                                               const float* __restrict__ wb,
                                               float* __restrict__ out) {
  const int n = threadIdx.x;
  const int tau = blockIdx.x;      // 0..70
  const int b = blockIdx.y;
  float s = wb[n];
#pragma unroll
  for (int j = 0; j < NT_; ++j) {
    s += R[(b * T_ + tau + j) * N_ + n] * wt[j * N_ + n];
  }
  out[((size_t)b * N_ + n) * TOUT + tau] = s;
}

extern "C" void kernel_launch(void* const* d_in, const int* in_sizes, int n_in,
                              void* d_out, int out_size, void* d_ws, size_t ws_size,
                              hipStream_t stream) {
  (void)in_sizes; (void)n_in; (void)out_size; (void)ws_size;
  const float* x    = (const float*)d_in[0];
  // d_in[1] = targets (unused by reference)
  const float* wc   = (const float*)d_in[2];
  const float* wx   = (const float*)d_in[3];
  const float* wy   = (const float*)d_in[4];
  const float* wsx  = (const float*)d_in[5];
  const float* wsy  = (const float*)d_in[6];
  const float* wt   = (const float*)d_in[7];
  const float* wb   = (const float*)d_in[8];
  float* out = (float*)d_out;

  char* ws = (char*)d_ws;
  unsigned short* Bp = (unsigned short*)ws;   // 2304*128*2 = 589824 B
  float* R = (float*)(ws + 589824);           // 320*128*4  = 163840 B

  hipMemsetAsync(R, 0, (size_t)B_ * T_ * N_ * sizeof(float), stream);
  k1_ws<<<N_, 256, 0, stream>>>(wx, wy, wsx, wsy, Bp);
  dim3 g2(B_ * T_, KSPLIT);
  k2_fused<<<g2, 256, 0, stream>>>(x, Bp, wc, R);
  dim3 g4(TOUT, B_);
  k4_conv<<<g4, 128, 0, stream>>>(R, wt, wb, out);
}

// Round 4
// 284.244 us; speedup vs baseline: 1.0520x; 1.0053x over previous
//
#include <hip/hip_runtime.h>
#include <hip/hip_bf16.h>
#include <stdint.h>

// Problem constants
#define B_ 4
#define C_ 64
#define T_ 80
#define H_ 36
#define W_ 64
#define N_ 128
#define NT_ 10
#define S_ (H_*W_)        // 2304 = K of the GEMM
#define M_ (B_*C_*T_)     // 20480 = rows of the GEMM
#define K_ S_
#define TOUT (T_-NT_+1)   // 71

#define BM 64             // = C_: one block owns all channels of one (b,t)
#define BK 64
#define KSPLIT 4
#define KCH (K_ / KSPLIT) // 576
#define NIT (KCH / BK)    // 9 iters

using float4v = __attribute__((ext_vector_type(4))) float;
using short8v = __attribute__((ext_vector_type(8))) short;

// round-to-nearest-even fp32 -> bf16 bits
__device__ __forceinline__ unsigned short f2bf(float f) {
  unsigned int u = __float_as_uint(f);
  u += 0x7fffu + ((u >> 16) & 1u);
  return (unsigned short)(u >> 16);
}

__device__ __forceinline__ unsigned int pkbf(float a, float b) {
  union { __hip_bfloat162 h2; unsigned int u; } cv;
  cv.h2 = __float22bfloat162_rn(make_float2(a, b));
  return cv.u;
}

// async global->LDS, 16B per lane (lds dest = wave-uniform base + lane*16)
__device__ __forceinline__ void glds16(const void* g, void* l) {
  __builtin_amdgcn_global_load_lds(
      (const __attribute__((address_space(1))) unsigned int*)g,
      (__attribute__((address_space(3))) unsigned int*)l, 16, 0, 0);
}

// ---------------------------------------------------------------------------
// K1: Gaussian soft-pool weights, normalized, written fragment-packed bf16:
//     Bp[((s>>3)*N + n)*8 + (s&7)]  i.e. [K/8][N][8]
// Also zero-inits R (k2 accumulates into it with atomics).
// ---------------------------------------------------------------------------
__global__ __launch_bounds__(256) void k1_ws(const float* __restrict__ wx,
                                             const float* __restrict__ wy,
                                             const float* __restrict__ wsigx,
                                             const float* __restrict__ wsigy,
                                             unsigned short* __restrict__ Bp,
                                             float* __restrict__ R) {
  const int n = blockIdx.x;
  const int tid = threadIdx.x;

  // zero R: 40960 floats over 128 blocks x 256 threads
  {
    const int g = n * 256 + tid;           // 0..32767
    R[g] = 0.f;
    if (g < B_ * T_ * N_ - 32768) R[g + 32768] = 0.f;
  }

  const float cx = wx[n], cy = wy[n];
  const float rx = fmaxf(wsigx[n], 0.f);
  const float ry = fmaxf(wsigy[n], 0.f);
  const float i2sx = 0.5f / (0.1f + rx * rx);
  const float i2sy = 0.5f / (0.1f + ry * ry);

  float ev[9];   // 2304 = 9*256, each thread owns s = tid + i*256
  float part = 0.f;
#pragma unroll
  for (int i = 0; i < 9; ++i) {
    const int s = tid + i * 256;
    const int h = s >> 6, w = s & 63;
    const float dx = (w - 31.5f) * (1.f / 64.f) - cx;  // (w - W/2 + .5)/W
    const float dy = (h - 17.5f) * (1.f / 36.f) - cy;  // (h - H/2 + .5)/H
    const float e = __expf(-(dx * dx * i2sx + dy * dy * i2sy));
    ev[i] = e;
    part += e;
  }
#pragma unroll
  for (int off = 32; off > 0; off >>= 1) part += __shfl_down(part, off);
  __shared__ float red[4];
  if ((tid & 63) == 0) red[tid >> 6] = part;
  __syncthreads();
  const float inv = 1.f / (0.1f + red[0] + red[1] + red[2] + red[3]);
#pragma unroll
  for (int i = 0; i < 9; ++i) {
    const int s = tid + i * 256;
    Bp[((s >> 3) * N_ + n) * 8 + (s & 7)] = f2bf(ev[i] * inv);
  }
}

// ---------------------------------------------------------------------------
// K2 (fused): for block (bt, split):
//   Z[c, n] = sum_{k in split} x[(b*C+c)*T+t, k] * ws[k, n]   (c = 0..63)
//   R[bt, n] += sum_c wc[c,n] * Z[c,n]      (atomicAdd of k-split partial)
// BM=64 x BN=128 x BK=64, 256 threads = 4 waves; wave wv owns cols wv*32..+31.
// A: fp32 LDS double-buffered, XOR-swizzled 16B chunks:
//    chunk(r,c4) at r*16 + (c4 ^ (r&15)).  B: bf16 frags direct from L2.
// B fragment loads are issued BEFORE the glds prefetch each iter so that
// consuming B needs only vmcnt(4) (prefetch stays in flight; vmcnt is FIFO).
// ---------------------------------------------------------------------------
__global__ __launch_bounds__(256, 4) void k2_fused(const float* __restrict__ A,
                                                   const unsigned short* __restrict__ Bp,
                                                   const float* __restrict__ wc,
                                                   float* __restrict__ R) {
  __shared__ float4v As[2][BM * 16];   // 2 x 16 KB
  const int tid = threadIdx.x;
  const int lane = tid & 63;
  const int wv = tid >> 6;             // wave's 32-col strip
  const int m15 = lane & 15;
  const int q = lane >> 4;
  const int bt = blockIdx.x;           // b*T + t
  const int b = bt / T_;
  const int t = bt - b * T_;
  const int split = blockIdx.y;
  const int kStart = split * KCH;

  // A staging: 1024 chunks/tile, 4 per thread; row r <-> channel c=r
  const float* ga[4];
  int lam_[4];
#pragma unroll
  for (int i = 0; i < 4; ++i) {
    const int lam = i * 256 + tid;
    const int r = lam >> 4;
    const int c4 = (lam & 15) ^ (r & 15);
    ga[i] = A + (size_t)((b * C_ + r) * T_ + t) * K_ + kStart + c4 * 4;
    lam_[i] = lam;
  }

  float4v acc[4][2];                   // [mt][nt]
#pragma unroll
  for (int i = 0; i < 4; ++i)
#pragma unroll
    for (int j = 0; j < 2; ++j) acc[i][j] = (float4v)(0.f);

  // prologue: stage k-tile 0 into buf 0
#pragma unroll
  for (int i = 0; i < 4; ++i) glds16(ga[i], &As[0][lam_[i]]);

  int cur = 0;
  for (int it = 0; it < NIT; ++it) {
    // B fragments for this iter: load FIRST (enter vmcnt queue before glds)
    short8v bfr[2][2];                 // [ks][nt]
    const int kg0 = (kStart + it * BK) >> 3;
#pragma unroll
    for (int ks = 0; ks < 2; ++ks) {
      const int kg = kg0 + ks * 4 + q;
      bfr[ks][0] = *(const short8v*)(Bp + ((size_t)kg * N_ + wv * 32 + m15) * 8);
      bfr[ks][1] = *(const short8v*)(Bp + ((size_t)kg * N_ + wv * 32 + 16 + m15) * 8);
    }

    __syncthreads();                   // buf[cur] ready for all waves
    if (it + 1 < NIT) {                // prefetch next tile into buf[cur^1]
#pragma unroll
      for (int i = 0; i < 4; ++i)
        glds16(ga[i] + (size_t)(it + 1) * BK, &As[cur ^ 1][lam_[i]]);
    }

#pragma unroll
    for (int ks = 0; ks < 2; ++ks) {
      const int c4a = ks * 8 + q * 2;
#pragma unroll
      for (int mt = 0; mt < 4; ++mt) {
        const int rowc = (mt * 16 + m15) * 16;
        const float4v alo = As[cur][rowc + (c4a ^ m15)];
        const float4v ahi = As[cur][rowc + ((c4a + 1) ^ m15)];
        union { short8v s8; unsigned int u[4]; } af;
        af.u[0] = pkbf(alo[0], alo[1]);
        af.u[1] = pkbf(alo[2], alo[3]);
        af.u[2] = pkbf(ahi[0], ahi[1]);
        af.u[3] = pkbf(ahi[2], ahi[3]);
        acc[mt][0] = __builtin_amdgcn_mfma_f32_16x16x32_bf16(af.s8, bfr[ks][0], acc[mt][0], 0, 0, 0);
        acc[mt][1] = __builtin_amdgcn_mfma_f32_16x16x32_bf16(af.s8, bfr[ks][1], acc[mt][1], 0, 0, 0);
      }
    }
    cur ^= 1;
  }

  // Epilogue: C/D layout col = lane&15, row = q*4 + reg; row == channel c.
  // partial over this lane's 16 channels, butterfly over q, one atomic per n.
#pragma unroll
  for (int nt = 0; nt < 2; ++nt) {
    const int n = wv * 32 + nt * 16 + m15;
    float p = 0.f;
#pragma unroll
    for (int mt = 0; mt < 4; ++mt)
#pragma unroll
      for (int v = 0; v < 4; ++v)
        p += acc[mt][nt][v] * wc[(mt * 16 + q * 4 + v) * N_ + n];
    p += __shfl_xor(p, 16);
    p += __shfl_xor(p, 32);
    if (q == 0) atomicAdd(&R[(size_t)bt * N_ + n], p);
  }
}

// ---------------------------------------------------------------------------
// K4: out[b,n,tau] = sum_j R[b, tau+j, n] * wt[j,n] + wb[n]
// ---------------------------------------------------------------------------
__global__ __launch_bounds__(128) void k4_conv(const float* __restrict__ R,
                                               const float* __restrict__ wt,
                                               const float* __restrict__ wb,
                                               float* __restrict__ out) {
  const int n = threadIdx.x;
  const int tau = blockIdx.x;      // 0..70
  const int b = blockIdx.y;
  float s = wb[n];
#pragma unroll
  for (int j = 0; j < NT_; ++j) {
    s += R[(b * T_ + tau + j) * N_ + n] * wt[j * N_ + n];
  }
  out[((size_t)b * N_ + n) * TOUT + tau] = s;
}

extern "C" void kernel_launch(void* const* d_in, const int* in_sizes, int n_in,
                              void* d_out, int out_size, void* d_ws, size_t ws_size,
                              hipStream_t stream) {
  (void)in_sizes; (void)n_in; (void)out_size; (void)ws_size;
  const float* x    = (const float*)d_in[0];
  // d_in[1] = targets (unused by reference)
  const float* wc   = (const float*)d_in[2];
  const float* wx   = (const float*)d_in[3];
  const float* wy   = (const float*)d_in[4];
  const float* wsx  = (const float*)d_in[5];
  const float* wsy  = (const float*)d_in[6];
  const float* wt   = (const float*)d_in[7];
  const float* wb   = (const float*)d_in[8];
  float* out = (float*)d_out;

  char* ws = (char*)d_ws;
  unsigned short* Bp = (unsigned short*)ws;   // 2304*128*2 = 589824 B
  float* R = (float*)(ws + 589824);           // 320*128*4  = 163840 B

  k1_ws<<<N_, 256, 0, stream>>>(wx, wy, wsx, wsy, Bp, R);
  dim3 g2(B_ * T_, KSPLIT);
  k2_fused<<<g2, 256, 0, stream>>>(x, Bp, wc, R);
  dim3 g4(TOUT, B_);
  k4_conv<<<g4, 128, 0, stream>>>(R, wt, wb, out);
}